// Round 3
// baseline (58.892 us; speedup 1.0000x reference)
//
#include <hip/hip_runtime.h>
#include <hip/hip_cooperative_groups.h>
#include <math.h>

namespace cg = cooperative_groups;

// Problem constants
#define BATCH   32
#define DIMN    96
#define KCOMP   64
#define NUM_IN  (DIMN*DIMN)   // 9216
#define NUM_OUT (DIMN*DIMN)   // 9216

// Workspace layout (floats):
//   G0[KCOMP][DIMN]  @ 0      -- out-dim-0 factor, pre-scaled by weights[k]
//   G1[KCOMP][DIMN]  @ 6144   -- out-dim-1 factor
//   Y [BATCH][KCOMP] @ 12288  -- x projected onto input Gaussians
#define G0_OFF 0
#define G1_OFF (KCOMP * DIMN)          // 6144
#define Y_OFF  (2 * KCOMP * DIMN)      // 12288

#define GRID_BLOCKS 288

// ---------------------------------------------------------------------------
// Single cooperative kernel.
// Phase 1 (blocks 0..255): factor tables + Y[b,k] projection.
//   - Blocks 0..47 additionally write G0/G1 (output-dim factor tables).
//   - Wave wid = bid*4+w handles (b = wid>>5, k = wid&31 and k+32): builds its
//     four 96-entry input-dim factor rows in LDS (~6 exps/lane), strides x[b]
//     coalesced, butterfly-reduces, writes Y to ws.
// grid.sync()
// Phase 2 (all 288 blocks): out[b,o] = bias[o] + sum_k Y[b,k]*G0[k][c]*G1[k][d]
//   - Block (p = bid>>1, h = bid&1): outputs o = p*64+lane (coalesced),
//     batch rows h*16 + bg*4 + j (bg = tid>>6, j = 0..3).
//   - Y staged in LDS (8 KB, broadcast reads); per k-iter 2 global loads
//     (L1/L2-resident) feed 4 FMAs per thread.
// ---------------------------------------------------------------------------
__global__ __launch_bounds__(256) void k_fused(const float* __restrict__ x,
                                               const float* __restrict__ mus,
                                               const float* __restrict__ log_vars,
                                               const float* __restrict__ weights,
                                               const float* __restrict__ bias,
                                               float* __restrict__ out,
                                               float* __restrict__ ws) {
    __shared__ float F[4][4][DIMN];        // phase-1 input-dim factor rows, 6 KB
    __shared__ float Ys[BATCH * KCOMP];    // phase-2 Y stage, 8 KB

    int tid = threadIdx.x;
    int bid = blockIdx.x;

    // ---- Phase 1, Part A: output-dim factor tables (12288 elements) ----
    if (bid < 48) {
        int idx = bid * 256 + tid;                 // 0..12287
        int dim = idx / (KCOMP * DIMN);            // 0 -> G0 (dim2), 1 -> G1 (dim3)
        int rem = idx - dim * (KCOMP * DIMN);
        int k   = rem / DIMN;
        int i   = rem - k * DIMN;
        float mu  = mus[k * 4 + 2 + dim];
        float var = expf(log_vars[k * 4 + 2 + dim]);
        float t   = (float)i * (1.0f / 95.0f) - mu;
        float v   = expf(-(t * t) / (2.0f * var));
        if (dim == 0) v *= weights[k];             // fold weights into G0
        ws[idx] = v;
    }

    // ---- Phase 1, Part B: Y[b,k] (blocks 0..255) ----
    if (bid < 256) {
        int w    = tid >> 6;
        int lane = tid & 63;
        int wid  = bid * 4 + w;                    // 0..1023
        int b    = wid >> 5;                       // 0..31
        int kk   = wid & 31;                       // handles kk, kk+32

        #pragma unroll
        for (int r = 0; r < 4; ++r) {              // r0:k,d0 r1:k+32,d0 r2:k,d1 r3:k+32,d1
            int k   = (r & 1) ? kk + 32 : kk;
            int dim = r >> 1;
            float mu = mus[k * 4 + dim];
            float rv = 0.5f / expf(log_vars[k * 4 + dim]);   // 1/(2 var)
            for (int i = lane; i < DIMN; i += 64) {
                float t = (float)i * (1.0f / 95.0f) - mu;
                F[w][r][i] = expf(-(t * t) * rv);
            }
        }
        __syncthreads();

        const float* xb = x + b * NUM_IN;
        float s0 = 0.0f, s1 = 0.0f;
        int i = lane, a = 0, d = lane;
        #pragma unroll 4
        for (int j = 0; j < NUM_IN / 64; ++j) {    // 144 iters
            float xv = xb[i];
            s0 = fmaf(xv * F[w][0][a], F[w][2][d], s0);
            s1 = fmaf(xv * F[w][1][a], F[w][3][d], s1);
            i += 64; d += 64;
            if (d >= DIMN) { d -= DIMN; ++a; }
        }
        #pragma unroll
        for (int off = 32; off > 0; off >>= 1) {
            s0 += __shfl_xor(s0, off, 64);
            s1 += __shfl_xor(s1, off, 64);
        }
        if (lane == 0) {
            ws[Y_OFF + b * KCOMP + kk]      = s0;
            ws[Y_OFF + b * KCOMP + kk + 32] = s1;
        }
    }

    // ---- grid-wide barrier (includes device memory fence) ----
    cg::this_grid().sync();

    // ---- Phase 2: outputs ----
    #pragma unroll
    for (int idx = tid; idx < BATCH * KCOMP; idx += 256)
        Ys[idx] = ws[Y_OFF + idx];
    __syncthreads();

    int lane = tid & 63;
    int bg   = tid >> 6;                           // 0..3
    int p    = bid >> 1;                           // 0..143 -> output group
    int h    = bid & 1;                            // batch half: rows h*16..h*16+15
    int o    = p * 64 + lane;
    int c    = o / DIMN;
    int d    = o - c * DIMN;
    int brow = h * 16 + bg * 4;                    // first of 4 batch rows

    const float* G0 = ws + G0_OFF;
    const float* G1 = ws + G1_OFF;

    float acc[4] = {0, 0, 0, 0};
    #pragma unroll 8
    for (int k = 0; k < KCOMP; ++k) {
        float ww = G0[k * DIMN + c] * G1[k * DIMN + d];
        #pragma unroll
        for (int j = 0; j < 4; ++j)
            acc[j] = fmaf(Ys[(brow + j) * KCOMP + k], ww, acc[j]);
    }

    float bs = bias[o];
    #pragma unroll
    for (int j = 0; j < 4; ++j)
        out[(brow + j) * NUM_OUT + o] = acc[j] + bs;
}

// ---------------------------------------------------------------------------
extern "C" void kernel_launch(void* const* d_in, const int* in_sizes, int n_in,
                              void* d_out, int out_size, void* d_ws, size_t ws_size,
                              hipStream_t stream) {
    const float* x        = (const float*)d_in[0];   // (32, 96, 96)
    const float* mus      = (const float*)d_in[1];   // (64, 4)
    const float* log_vars = (const float*)d_in[2];   // (64, 4)
    const float* weights  = (const float*)d_in[3];   // (64,)
    const float* bias     = (const float*)d_in[4];   // (9216,)
    float* out = (float*)d_out;                      // (32, 96, 96)
    float* ws  = (float*)d_ws;

    void* args[] = {(void*)&x, (void*)&mus, (void*)&log_vars, (void*)&weights,
                    (void*)&bias, (void*)&out, (void*)&ws};
    hipLaunchCooperativeKernel((const void*)k_fused, dim3(GRID_BLOCKS), dim3(256),
                               args, 0, stream);
}

// Round 4
// 23.230 us; speedup vs baseline: 2.5352x; 2.5352x over previous
//
#include <hip/hip_runtime.h>
#include <math.h>

// Problem constants
#define BATCH   32
#define DIMN    96
#define KCOMP   64
#define NUM_IN  (DIMN*DIMN)   // 9216
#define NUM_OUT (DIMN*DIMN)   // 9216

// Grid: 256 blocks = (b = bid>>3) x (oc = bid&7), 384 threads (6 waves).
// Each block independently computes out[b, c in oc*12..+11, all d].
//
// LDS plan (63,232 B):
//   lds[0     .. 9215 ]  xrow[96][96]    (phase 1-2)   -> G1[64][96] (phase 3-4)
//   lds[9216  .. 15359]  f1[96][64]      (phase 1-2)   -> G0[64][12] (phase 3-4)
//   lds[15360 .. 15743]  part[6][64]
//   lds[15744 .. 15807]  Yk[64]
#define LDS_FLOATS (NUM_IN + DIMN*KCOMP + 6*KCOMP + KCOMP)

__global__ __launch_bounds__(384) void k_gauss(const float* __restrict__ x,
                                               const float* __restrict__ mus,
                                               const float* __restrict__ log_vars,
                                               const float* __restrict__ weights,
                                               const float* __restrict__ bias,
                                               float* __restrict__ out) {
    __shared__ float lds[LDS_FLOATS];
    float* xrow = lds;                      // [96][96] (aliased by G1 later)
    float* f1   = lds + NUM_IN;             // [e][k] = [96][64] (aliased by G0 later)
    float* G1   = lds;                      // [k][d] = [64][96]
    float* G0   = lds + NUM_IN;             // [k][cl] = [64][12]
    float* part = lds + NUM_IN + DIMN*KCOMP;   // [6][64]
    float* Yk   = part + 6*KCOMP;              // [64]

    const int tid = threadIdx.x;
    const int bid = blockIdx.x;
    const int b   = bid >> 3;               // batch row
    const int oc  = bid & 7;                // output-column eighth (12 c's)

    // ---- Phase 1: stage x[b] into LDS + build f1 table (input dim 1) ----
    {
        const float4* xg = (const float4*)(x + b * NUM_IN);
        float4* xl = (float4*)xrow;
        #pragma unroll
        for (int i = tid; i < NUM_IN / 4; i += 384) xl[i] = xg[i];

        for (int idx = tid; idx < DIMN * KCOMP; idx += 384) {
            int e = idx >> 6;               // [e][k] layout
            int k = idx & 63;
            float mu = mus[k * 4 + 1];
            float rv = 0.5f * expf(-log_vars[k * 4 + 1]);   // 1/(2 var)
            float t  = (float)e * (1.0f / 95.0f) - mu;
            f1[idx] = expf(-(t * t) * rv);
        }
    }
    __syncthreads();

    // ---- Phase 2: Y partials. lane = k; wave w handles a = w*16 .. w*16+15 ----
    {
        const int w    = tid >> 6;
        const int lane = tid & 63;
        const int a0   = w * 16;

        float mu0 = mus[lane * 4 + 0];
        float rv0 = 0.5f * expf(-log_vars[lane * 4 + 0]);

        float t[16];
        #pragma unroll
        for (int i = 0; i < 16; ++i) t[i] = 0.0f;

        for (int e4 = 0; e4 < DIMN / 4; ++e4) {    // 24 iterations
            float f1v0 = f1[(e4 * 4 + 0) * 64 + lane];
            float f1v1 = f1[(e4 * 4 + 1) * 64 + lane];
            float f1v2 = f1[(e4 * 4 + 2) * 64 + lane];
            float f1v3 = f1[(e4 * 4 + 3) * 64 + lane];
            #pragma unroll
            for (int i = 0; i < 16; ++i) {
                const float4 xv = *(const float4*)&xrow[(a0 + i) * DIMN + e4 * 4];
                t[i] = fmaf(xv.x, f1v0, t[i]);
                t[i] = fmaf(xv.y, f1v1, t[i]);
                t[i] = fmaf(xv.z, f1v2, t[i]);
                t[i] = fmaf(xv.w, f1v3, t[i]);
            }
        }
        float yp = 0.0f;
        #pragma unroll
        for (int i = 0; i < 16; ++i) {
            float ga = (float)(a0 + i) * (1.0f / 95.0f) - mu0;
            yp = fmaf(expf(-(ga * ga) * rv0), t[i], yp);
        }
        part[w * 64 + lane] = yp;
    }
    __syncthreads();

    // ---- Phase 3: reduce Y; build G0 (this block's 12 c's) and G1 tables ----
    // (f1 and xrow are dead now; G0/G1 alias them.)
    for (int idx = tid; idx < KCOMP * DIMN; idx += 384) {   // G1[k][d]
        int k = idx / DIMN;
        int d = idx - k * DIMN;
        float mu = mus[k * 4 + 3];
        float rv = 0.5f * expf(-log_vars[k * 4 + 3]);
        float t  = (float)d * (1.0f / 95.0f) - mu;
        G1[idx] = expf(-(t * t) * rv);
    }
    for (int idx = tid; idx < KCOMP * 12; idx += 384) {     // G0[k][cl], w-scaled
        int k  = idx / 12;
        int cl = idx - k * 12;
        int c  = oc * 12 + cl;
        float mu = mus[k * 4 + 2];
        float rv = 0.5f * expf(-log_vars[k * 4 + 2]);
        float t  = (float)c * (1.0f / 95.0f) - mu;
        G0[idx] = weights[k] * expf(-(t * t) * rv);
    }
    if (tid < KCOMP) {
        float s = 0.0f;
        #pragma unroll
        for (int w = 0; w < 6; ++w) s += part[w * 64 + tid];
        Yk[tid] = s;
    }
    __syncthreads();

    // ---- Phase 4: outputs. thread = (cl = tid>>5, dsub = tid&31), 3 d's each ----
    {
        const int cl   = tid >> 5;          // 0..11
        const int dsub = tid & 31;          // 0..31
        const int c    = oc * 12 + cl;
        const int d0   = dsub * 3;

        float acc0 = 0.0f, acc1 = 0.0f, acc2 = 0.0f;
        #pragma unroll 8
        for (int k = 0; k < KCOMP; ++k) {
            float wk = Yk[k] * G0[k * 12 + cl];
            acc0 = fmaf(wk, G1[k * DIMN + d0 + 0], acc0);
            acc1 = fmaf(wk, G1[k * DIMN + d0 + 1], acc1);
            acc2 = fmaf(wk, G1[k * DIMN + d0 + 2], acc2);
        }
        const int o = c * DIMN + d0;
        float* ob = out + b * NUM_OUT + o;
        ob[0] = acc0 + bias[o + 0];
        ob[1] = acc1 + bias[o + 1];
        ob[2] = acc2 + bias[o + 2];
    }
}

// ---------------------------------------------------------------------------
extern "C" void kernel_launch(void* const* d_in, const int* in_sizes, int n_in,
                              void* d_out, int out_size, void* d_ws, size_t ws_size,
                              hipStream_t stream) {
    const float* x        = (const float*)d_in[0];   // (32, 96, 96)
    const float* mus      = (const float*)d_in[1];   // (64, 4)
    const float* log_vars = (const float*)d_in[2];   // (64, 4)
    const float* weights  = (const float*)d_in[3];   // (64,)
    const float* bias     = (const float*)d_in[4];   // (9216,)
    float* out = (float*)d_out;                      // (32, 96, 96)

    k_gauss<<<256, 384, 0, stream>>>(x, mus, log_vars, weights, bias, out);
}

// Round 5
// 16.434 us; speedup vs baseline: 3.5836x; 1.4136x over previous
//
#include <hip/hip_runtime.h>
#include <math.h>

// Problem constants
#define BATCH   32
#define DIMN    96
#define KCOMP   64
#define NUM_IN  (DIMN*DIMN)   // 9216
#define NUM_OUT (DIMN*DIMN)   // 9216

// ws layout: Yp[32][8][64] floats (partial projections, pre-f0-weighted sums
// over each block's 12 a-rows).
//
// Math (fp32 throughout, same as rounds 1-4 which passed at absmax 0.0625):
//   f_dim[k][i] = exp(-(i/95 - mu[k,dim])^2 * 0.5*exp(-log_var[k,dim]))
//   Y[b,k]  = sum_a f0[k][a] * sum_e x[b,a,e] * f1[k][e]
//   out[b,c,d] = bias[c,d] + sum_k (weights[k]*Y[b,k]) * f2[k][c] * f3[k][d]

// ---------------------------------------------------------------------------
// Kernel A: projection partials. Block = (b = bid>>3, aq = bid&7) handles
// a-rows aq*12 .. aq*12+11 (3 rows per wave). lane = k.
// ---------------------------------------------------------------------------
__global__ __launch_bounds__(256) void kA(const float* __restrict__ x,
                                          const float* __restrict__ mus,
                                          const float* __restrict__ log_vars,
                                          float* __restrict__ Yp) {
    __shared__ float f1[DIMN * KCOMP];     // [e][k], 24 KB
    __shared__ float part[4][KCOMP];

    const int tid = threadIdx.x;
    const int bid = blockIdx.x;
    const int b   = bid >> 3;
    const int aq  = bid & 7;

    // build f1 table (input dim 1): conflict-free consecutive writes
    for (int idx = tid; idx < DIMN * KCOMP; idx += 256) {
        int e = idx >> 6;
        int k = idx & 63;
        float mu = mus[k * 4 + 1];
        float rv = 0.5f * expf(-log_vars[k * 4 + 1]);
        float t  = (float)e * (1.0f / 95.0f) - mu;
        f1[idx] = expf(-(t * t) * rv);
    }
    __syncthreads();

    const int w    = tid >> 6;             // wave 0..3
    const int lane = tid & 63;             // = k
    const int a0   = aq * 12 + w * 3;      // first of this wave's 3 a-rows

    const float* xr = x + b * NUM_IN + a0 * DIMN;

    float acc0 = 0.0f, acc1 = 0.0f, acc2 = 0.0f;
    #pragma unroll 4
    for (int e4 = 0; e4 < DIMN / 4; ++e4) {            // 24 iters
        float f10 = f1[(e4 * 4 + 0) * 64 + lane];
        float f11 = f1[(e4 * 4 + 1) * 64 + lane];
        float f12 = f1[(e4 * 4 + 2) * 64 + lane];
        float f13 = f1[(e4 * 4 + 3) * 64 + lane];
        const float4 x0 = *(const float4*)(xr + 0 * DIMN + e4 * 4);  // wave-broadcast
        const float4 x1 = *(const float4*)(xr + 1 * DIMN + e4 * 4);
        const float4 x2 = *(const float4*)(xr + 2 * DIMN + e4 * 4);
        acc0 = fmaf(x0.x, f10, acc0); acc0 = fmaf(x0.y, f11, acc0);
        acc0 = fmaf(x0.z, f12, acc0); acc0 = fmaf(x0.w, f13, acc0);
        acc1 = fmaf(x1.x, f10, acc1); acc1 = fmaf(x1.y, f11, acc1);
        acc1 = fmaf(x1.z, f12, acc1); acc1 = fmaf(x1.w, f13, acc1);
        acc2 = fmaf(x2.x, f10, acc2); acc2 = fmaf(x2.y, f11, acc2);
        acc2 = fmaf(x2.z, f12, acc2); acc2 = fmaf(x2.w, f13, acc2);
    }

    // fold f0 (input dim 0) for this lane's k over the 3 a-rows
    float mu0 = mus[lane * 4 + 0];
    float rv0 = 0.5f * expf(-log_vars[lane * 4 + 0]);
    float g0 = (float)(a0 + 0) * (1.0f / 95.0f) - mu0;
    float g1 = (float)(a0 + 1) * (1.0f / 95.0f) - mu0;
    float g2 = (float)(a0 + 2) * (1.0f / 95.0f) - mu0;
    float yp = expf(-(g0 * g0) * rv0) * acc0
             + expf(-(g1 * g1) * rv0) * acc1
             + expf(-(g2 * g2) * rv0) * acc2;

    part[w][lane] = yp;
    __syncthreads();
    if (tid < KCOMP) {
        float s = part[0][tid] + part[1][tid] + part[2][tid] + part[3][tid];
        Yp[(b * 8 + aq) * KCOMP + tid] = s;
    }
}

// ---------------------------------------------------------------------------
// Kernel B: outputs. Block = (b = bid>>3, oc = bid&7) covers c = oc*12..+11,
// all 96 d. 320 threads (5 waves).
// Main compute: 288 active threads = (kh in 0..1, p in 0..5, dq in 0..23);
// thread accumulates 2 c x 4 d over its 32-k half; halves combined in LDS.
// ---------------------------------------------------------------------------
__global__ __launch_bounds__(320) void kB(const float* __restrict__ mus,
                                          const float* __restrict__ log_vars,
                                          const float* __restrict__ weights,
                                          const float* __restrict__ bias,
                                          const float* __restrict__ Yp,
                                          float* __restrict__ out) {
    __shared__ float G1[KCOMP * DIMN];     // [k][d], 24 KB
    __shared__ float YG0[KCOMP * 12];      // [k][cl], weights*Y folded, 3 KB
    __shared__ float Yw[KCOMP];
    __shared__ float pacc[2][144][8];      // 9 KB

    const int tid = threadIdx.x;
    const int bid = blockIdx.x;
    const int b   = bid >> 3;
    const int oc  = bid & 7;

    // Yw[k] = weights[k] * sum_aq Yp[b][aq][k]
    if (tid < KCOMP) {
        float s = 0.0f;
        #pragma unroll
        for (int q = 0; q < 8; ++q) s += Yp[(b * 8 + q) * KCOMP + tid];
        Yw[tid] = s * weights[tid];
    }
    // G1 (output dim 1) table
    for (int idx = tid; idx < KCOMP * DIMN; idx += 320) {
        int k = idx / DIMN;
        int d = idx - k * DIMN;
        float mu = mus[k * 4 + 3];
        float rv = 0.5f * expf(-log_vars[k * 4 + 3]);
        float t  = (float)d * (1.0f / 95.0f) - mu;
        G1[idx] = expf(-(t * t) * rv);
    }
    __syncthreads();

    // YG0[k][cl] = Yw[k] * f2[k][oc*12+cl]
    for (int idx = tid; idx < KCOMP * 12; idx += 320) {
        int k  = idx / 12;
        int cl = idx - k * 12;
        int c  = oc * 12 + cl;
        float mu = mus[k * 4 + 2];
        float rv = 0.5f * expf(-log_vars[k * 4 + 2]);
        float t  = (float)c * (1.0f / 95.0f) - mu;
        YG0[idx] = Yw[k] * expf(-(t * t) * rv);
    }
    __syncthreads();

    // main rank-64 update, split over 2 k-halves
    if (tid < 288) {
        const int kh = tid / 144;
        const int r  = tid - kh * 144;
        const int p  = r / 24;             // c-pair 0..5
        const int dq = r - p * 24;         // d-quad 0..23

        float a0 = 0, a1 = 0, a2 = 0, a3 = 0, a4 = 0, a5 = 0, a6 = 0, a7 = 0;
        #pragma unroll 8
        for (int kk = 0; kk < 32; ++kk) {
            int k = kh * 32 + kk;
            const float4 g = *(const float4*)&G1[k * DIMN + dq * 4];
            const float2 y = *(const float2*)&YG0[k * 12 + p * 2];
            a0 = fmaf(y.x, g.x, a0); a1 = fmaf(y.x, g.y, a1);
            a2 = fmaf(y.x, g.z, a2); a3 = fmaf(y.x, g.w, a3);
            a4 = fmaf(y.y, g.x, a4); a5 = fmaf(y.y, g.y, a5);
            a6 = fmaf(y.y, g.z, a6); a7 = fmaf(y.y, g.w, a7);
        }
        float4* pa = (float4*)pacc[kh][r];
        pa[0] = make_float4(a0, a1, a2, a3);
        pa[1] = make_float4(a4, a5, a6, a7);
    }
    __syncthreads();

    // combine halves + bias + store (2 rows of float4 per thread)
    if (tid < 144) {
        const int p  = tid / 24;
        const int dq = tid - p * 24;
        const int c0 = oc * 12 + p * 2;
        const int d0 = dq * 4;

        const float4* pa0 = (const float4*)pacc[0][tid];
        const float4* pa1 = (const float4*)pacc[1][tid];

        #pragma unroll
        for (int j = 0; j < 2; ++j) {
            float4 v  = pa0[j];
            float4 w2 = pa1[j];
            int o = (c0 + j) * DIMN + d0;
            float4 bs = *(const float4*)&bias[o];
            float4 res = make_float4(v.x + w2.x + bs.x, v.y + w2.y + bs.y,
                                     v.z + w2.z + bs.z, v.w + w2.w + bs.w);
            *(float4*)&out[b * NUM_OUT + o] = res;
        }
    }
}

// ---------------------------------------------------------------------------
extern "C" void kernel_launch(void* const* d_in, const int* in_sizes, int n_in,
                              void* d_out, int out_size, void* d_ws, size_t ws_size,
                              hipStream_t stream) {
    const float* x        = (const float*)d_in[0];   // (32, 96, 96)
    const float* mus      = (const float*)d_in[1];   // (64, 4)
    const float* log_vars = (const float*)d_in[2];   // (64, 4)
    const float* weights  = (const float*)d_in[3];   // (64,)
    const float* bias     = (const float*)d_in[4];   // (9216,)
    float* out = (float*)d_out;                      // (32, 96, 96)
    float* Yp  = (float*)d_ws;                       // 32*8*64 floats

    kA<<<256, 256, 0, stream>>>(x, mus, log_vars, Yp);
    kB<<<256, 320, 0, stream>>>(mus, log_vars, weights, bias, Yp, out);
}

// Round 6
// 14.465 us; speedup vs baseline: 4.0714x; 1.1361x over previous
//
#include <hip/hip_runtime.h>
#include <math.h>

// Problem constants
#define BATCH   32
#define DIMN    96
#define KCOMP   64
#define NUM_IN  (DIMN*DIMN)   // 9216
#define NUM_OUT (DIMN*DIMN)   // 9216

// ws layout (floats):
//   Yp[32][8][64] @ 0      : partial projections per (b, a-twelfth)
//   F2[64][96]    @ 16384  : out-dim-0 factor, weights folded in
//   F3[64][96]    @ 22528  : out-dim-1 factor
#define YP_OFF 0
#define F2_OFF 16384
#define F3_OFF 22528

// Math (fp32 throughout; identical formulas to R5 which passed at 0.0625):
//   f_dim[k][i] = exp(-(i/95 - mu[k,dim])^2 * 0.5*exp(-log_var[k,dim]))
//   Y[b,k]      = sum_a f0[k][a] * sum_e x[b,a,e] * f1[k][e]
//   out[b,c,d]  = bias[c,d] + sum_k (w[k]*Y[b,k]) * f2[k][c] * f3[k][d]

// ---------------------------------------------------------------------------
// Kernel A: 280 blocks x 512 threads.
//  - Blocks 0..255: projection partials. Block = (b = bid>>3, aq = bid&7),
//    wave w: row-group rg = w>>1 (3 a-rows), e-half eh = w&1 (48 e's). lane = k.
//  - Blocks 256..279: build F2/F3 tables into ws (1 element/thread).
// ---------------------------------------------------------------------------
__global__ __launch_bounds__(512) void kA(const float* __restrict__ x,
                                          const float* __restrict__ mus,
                                          const float* __restrict__ log_vars,
                                          const float* __restrict__ weights,
                                          float* __restrict__ ws) {
    const int tid = threadIdx.x;
    const int bid = blockIdx.x;

    if (bid >= 256) {                       // ---- table blocks ----
        int idx = (bid - 256) * 512 + tid;  // 0..12287
        int half = idx >= (KCOMP * DIMN);
        int t = idx - half * (KCOMP * DIMN);
        int k = t / DIMN;
        int i = t - k * DIMN;
        int dim = 2 + half;
        float mu = mus[k * 4 + dim];
        float rv = 0.5f * expf(-log_vars[k * 4 + dim]);
        float g  = (float)i * (1.0f / 95.0f) - mu;
        float v  = expf(-(g * g) * rv);
        if (!half) v *= weights[k];         // fold weights into F2
        ws[(half ? F3_OFF : F2_OFF) + t] = v;
        return;
    }

    __shared__ float f1[DIMN * KCOMP];      // [e][k], 24 KB
    __shared__ float part[8][KCOMP];        // 2 KB

    const int b  = bid >> 3;
    const int aq = bid & 7;

    // build f1 (input dim 1): k = tid&63 is loop-invariant
    {
        const int k  = tid & 63;
        const int e0 = tid >> 6;            // 0..7
        float mu = mus[k * 4 + 1];
        float rv = 0.5f * expf(-log_vars[k * 4 + 1]);
        #pragma unroll
        for (int j = 0; j < 12; ++j) {
            int e = e0 + j * 8;
            float t = (float)e * (1.0f / 95.0f) - mu;
            f1[e * 64 + k] = expf(-(t * t) * rv);
        }
    }
    __syncthreads();

    const int w    = tid >> 6;              // 0..7
    const int lane = tid & 63;              // = k
    const int rg   = w >> 1;                // 0..3
    const int eh   = w & 1;                 // e-half
    const int a0   = aq * 12 + rg * 3;

    const float* xr = x + b * NUM_IN + a0 * DIMN;

    float acc0 = 0.0f, acc1 = 0.0f, acc2 = 0.0f;
    #pragma unroll 4
    for (int e4 = eh * 12; e4 < eh * 12 + 12; ++e4) {
        float f10 = f1[(e4 * 4 + 0) * 64 + lane];
        float f11 = f1[(e4 * 4 + 1) * 64 + lane];
        float f12 = f1[(e4 * 4 + 2) * 64 + lane];
        float f13 = f1[(e4 * 4 + 3) * 64 + lane];
        const float4 x0 = *(const float4*)(xr + 0 * DIMN + e4 * 4);  // broadcast
        const float4 x1 = *(const float4*)(xr + 1 * DIMN + e4 * 4);
        const float4 x2 = *(const float4*)(xr + 2 * DIMN + e4 * 4);
        acc0 = fmaf(x0.x, f10, acc0); acc0 = fmaf(x0.y, f11, acc0);
        acc0 = fmaf(x0.z, f12, acc0); acc0 = fmaf(x0.w, f13, acc0);
        acc1 = fmaf(x1.x, f10, acc1); acc1 = fmaf(x1.y, f11, acc1);
        acc1 = fmaf(x1.z, f12, acc1); acc1 = fmaf(x1.w, f13, acc1);
        acc2 = fmaf(x2.x, f10, acc2); acc2 = fmaf(x2.y, f11, acc2);
        acc2 = fmaf(x2.z, f12, acc2); acc2 = fmaf(x2.w, f13, acc2);
    }

    // fold f0 (input dim 0) for this lane's k over the 3 a-rows
    float mu0 = mus[lane * 4 + 0];
    float rv0 = 0.5f * expf(-log_vars[lane * 4 + 0]);
    float g0 = (float)(a0 + 0) * (1.0f / 95.0f) - mu0;
    float g1 = (float)(a0 + 1) * (1.0f / 95.0f) - mu0;
    float g2 = (float)(a0 + 2) * (1.0f / 95.0f) - mu0;
    float yp = expf(-(g0 * g0) * rv0) * acc0
             + expf(-(g1 * g1) * rv0) * acc1
             + expf(-(g2 * g2) * rv0) * acc2;

    part[w][lane] = yp;
    __syncthreads();
    if (tid < KCOMP) {
        float s = 0.0f;
        #pragma unroll
        for (int q = 0; q < 8; ++q) s += part[q][tid];
        ws[YP_OFF + (b * 8 + aq) * KCOMP + tid] = s;
    }
}

// ---------------------------------------------------------------------------
// Kernel B: 256 blocks (b = bid>>3, oc = bid&7) x 576 threads. No exps.
//  - Stage G1 = F3 (float4 copies), build YG0[k][cl] = (sum_q Yp[b][q][k]) *
//    F2[k][oc*12+cl]  (weights already folded into F2).
//  - Main: thread = (kq = tid/144, p = c-pair 0..5, dq = d-quad 0..23);
//    16 k-iters of {ds_read_b128 + ds_read_b64 -> 8 FMA}. Partials to pacc
//    (9-float stride: conflict-free b32), combined by 144 threads.
// ---------------------------------------------------------------------------
__global__ __launch_bounds__(576) void kB(const float* __restrict__ ws,
                                          const float* __restrict__ bias,
                                          float* __restrict__ out) {
    __shared__ float G1[KCOMP * DIMN];      // [k][d], 24 KB
    __shared__ float YG0[KCOMP * 12];       // [k][cl], 3 KB
    __shared__ float pacc[4 * 144 * 9];     // 20.25 KB

    const int tid = threadIdx.x;
    const int bid = blockIdx.x;
    const int b   = bid >> 3;
    const int oc  = bid & 7;

    // stage G1 <- F3 (global, L2-hot) as float4
    {
        const float4* F3g = (const float4*)(ws + F3_OFF);
        float4* G1v = (float4*)G1;
        #pragma unroll
        for (int i = tid; i < (KCOMP * DIMN) / 4; i += 576) G1v[i] = F3g[i];
    }
    // YG0[k][cl] = (sum_q Yp[b][q][k]) * F2[k][oc*12+cl]
    {
        const float* F2g = ws + F2_OFF;
        const float* Ypb = ws + YP_OFF + b * 8 * KCOMP;
        for (int idx = tid; idx < KCOMP * 12; idx += 576) {
            int k  = idx / 12;
            int cl = idx - k * 12;
            float s = 0.0f;
            #pragma unroll
            for (int q = 0; q < 8; ++q) s += Ypb[q * KCOMP + k];
            YG0[idx] = s * F2g[k * DIMN + oc * 12 + cl];
        }
    }
    __syncthreads();

    // main rank-64 update, k split 4 ways
    {
        const int kq = tid / 144;           // 0..3
        const int r  = tid - kq * 144;      // 0..143
        const int p  = r / 24;              // c-pair
        const int dq = r - p * 24;          // d-quad
        const int k0 = kq * 16;

        float a0 = 0, a1 = 0, a2 = 0, a3 = 0, a4 = 0, a5 = 0, a6 = 0, a7 = 0;
        #pragma unroll 8
        for (int kk = 0; kk < 16; ++kk) {
            int k = k0 + kk;
            const float4 g = *(const float4*)&G1[k * DIMN + dq * 4];
            const float2 y = *(const float2*)&YG0[k * 12 + p * 2];
            a0 = fmaf(y.x, g.x, a0); a1 = fmaf(y.x, g.y, a1);
            a2 = fmaf(y.x, g.z, a2); a3 = fmaf(y.x, g.w, a3);
            a4 = fmaf(y.y, g.x, a4); a5 = fmaf(y.y, g.y, a5);
            a6 = fmaf(y.y, g.z, a6); a7 = fmaf(y.y, g.w, a7);
        }
        float* pa = &pacc[(kq * 144 + r) * 9];
        pa[0] = a0; pa[1] = a1; pa[2] = a2; pa[3] = a3;
        pa[4] = a4; pa[5] = a5; pa[6] = a6; pa[7] = a7;
    }
    __syncthreads();

    // combine 4 k-partials + bias + store
    if (tid < 144) {
        const int p  = tid / 24;
        const int dq = tid - p * 24;
        const int c0 = oc * 12 + p * 2;
        const int d0 = dq * 4;

        float s[8];
        #pragma unroll
        for (int j = 0; j < 8; ++j) {
            s[j] = pacc[(0 * 144 + tid) * 9 + j] + pacc[(1 * 144 + tid) * 9 + j]
                 + pacc[(2 * 144 + tid) * 9 + j] + pacc[(3 * 144 + tid) * 9 + j];
        }
        #pragma unroll
        for (int jr = 0; jr < 2; ++jr) {
            int o = (c0 + jr) * DIMN + d0;
            float4 bs = *(const float4*)&bias[o];
            *(float4*)&out[b * NUM_OUT + o] =
                make_float4(s[jr * 4 + 0] + bs.x, s[jr * 4 + 1] + bs.y,
                            s[jr * 4 + 2] + bs.z, s[jr * 4 + 3] + bs.w);
        }
    }
}

// ---------------------------------------------------------------------------
extern "C" void kernel_launch(void* const* d_in, const int* in_sizes, int n_in,
                              void* d_out, int out_size, void* d_ws, size_t ws_size,
                              hipStream_t stream) {
    const float* x        = (const float*)d_in[0];   // (32, 96, 96)
    const float* mus      = (const float*)d_in[1];   // (64, 4)
    const float* log_vars = (const float*)d_in[2];   // (64, 4)
    const float* weights  = (const float*)d_in[3];   // (64,)
    const float* bias     = (const float*)d_in[4];   // (9216,)
    float* out = (float*)d_out;                      // (32, 96, 96)
    float* ws  = (float*)d_ws;

    kA<<<280, 512, 0, stream>>>(x, mus, log_vars, weights, ws);
    kB<<<256, 576, 0, stream>>>(ws, bias, out);
}

// Round 7
// 13.999 us; speedup vs baseline: 4.2068x; 1.0333x over previous
//
#include <hip/hip_runtime.h>
#include <math.h>

// Problem constants
#define BATCH   32
#define DIMN    96
#define KCOMP   64
#define NUM_IN  (DIMN*DIMN)   // 9216
#define NUM_OUT (DIMN*DIMN)   // 9216

// ws layout (floats):
//   Yp[32][8][64] @ 0      : partial projections per (b, a-twelfth)
//   F2[64][96]    @ 16384  : out-dim-0 factor, weights folded in
//   F3[64][96]    @ 22528  : out-dim-1 factor
#define YP_OFF 0
#define F2_OFF 16384
#define F3_OFF 22528

// Math (fp32 throughout; identical formulas to R5/R6 which passed at 0.0625):
//   f_dim[k][i] = exp(-(i/95 - mu[k,dim])^2 * 0.5*exp(-log_var[k,dim]))
//   Y[b,k]      = sum_a f0[k][a] * sum_e x[b,a,e] * f1[k][e]
//   out[b,c,d]  = bias[c,d] + sum_k (w[k]*Y[b,k]) * f2[k][c] * f3[k][d]

// ---------------------------------------------------------------------------
// Kernel A: 280 blocks x 512 threads.
//  - Blocks 0..255: projection partials. Block = (b = bid>>3, aq = bid&7),
//    12 a-rows staged in LDS (coalesced float4), f1 table in LDS; wave w:
//    row-group rg = w>>1 (3 rows), e-half eh = w&1 (48 e's), lane = k.
//    Main loop is pure LDS: x via same-address broadcast, f1 lane-strided.
//  - Blocks 256..279: build F2/F3 tables into ws (1 element/thread).
// ---------------------------------------------------------------------------
__global__ __launch_bounds__(512) void kA(const float* __restrict__ x,
                                          const float* __restrict__ mus,
                                          const float* __restrict__ log_vars,
                                          const float* __restrict__ weights,
                                          float* __restrict__ ws) {
    const int tid = threadIdx.x;
    const int bid = blockIdx.x;

    if (bid >= 256) {                       // ---- table blocks ----
        int idx = (bid - 256) * 512 + tid;  // 0..12287
        int half = idx >= (KCOMP * DIMN);
        int t = idx - half * (KCOMP * DIMN);
        int k = t / DIMN;
        int i = t - k * DIMN;
        int dim = 2 + half;
        float mu = mus[k * 4 + dim];
        float rv = 0.5f * expf(-log_vars[k * 4 + dim]);
        float g  = (float)i * (1.0f / 95.0f) - mu;
        float v  = expf(-(g * g) * rv);
        if (!half) v *= weights[k];         // fold weights into F2
        ws[(half ? F3_OFF : F2_OFF) + t] = v;
        return;
    }

    __shared__ float f1[DIMN * KCOMP];      // [e][k], 24 KB
    __shared__ float xs[12 * DIMN];         // 12 staged a-rows, 4.5 KB
    __shared__ float part[8][KCOMP];        // 2 KB

    const int b  = bid >> 3;
    const int aq = bid & 7;

    // stage this block's 12 x-rows: 288 coalesced float4 loads
    {
        const float4* xg = (const float4*)(x + b * NUM_IN + aq * 12 * DIMN);
        if (tid < 288) ((float4*)xs)[tid] = xg[tid];
    }
    // build f1 (input dim 1): k = tid&63 is loop-invariant
    {
        const int k  = tid & 63;
        const int e0 = tid >> 6;            // 0..7
        float mu = mus[k * 4 + 1];
        float rv = 0.5f * expf(-log_vars[k * 4 + 1]);
        #pragma unroll
        for (int j = 0; j < 12; ++j) {
            int e = e0 + j * 8;
            float t = (float)e * (1.0f / 95.0f) - mu;
            f1[e * 64 + k] = expf(-(t * t) * rv);
        }
    }
    __syncthreads();

    const int w    = tid >> 6;              // 0..7
    const int lane = tid & 63;              // = k
    const int rg   = w >> 1;                // 0..3
    const int eh   = w & 1;                 // e-half
    const int a0   = aq * 12 + rg * 3;

    const float* xr = xs + (rg * 3) * DIMN; // this wave's 3 rows (LDS)

    float acc0 = 0.0f, acc1 = 0.0f, acc2 = 0.0f;
    #pragma unroll 4
    for (int e4 = eh * 12; e4 < eh * 12 + 12; ++e4) {
        float f10 = f1[(e4 * 4 + 0) * 64 + lane];
        float f11 = f1[(e4 * 4 + 1) * 64 + lane];
        float f12 = f1[(e4 * 4 + 2) * 64 + lane];
        float f13 = f1[(e4 * 4 + 3) * 64 + lane];
        const float4 x0 = *(const float4*)(xr + 0 * DIMN + e4 * 4);  // LDS broadcast
        const float4 x1 = *(const float4*)(xr + 1 * DIMN + e4 * 4);
        const float4 x2 = *(const float4*)(xr + 2 * DIMN + e4 * 4);
        acc0 = fmaf(x0.x, f10, acc0); acc0 = fmaf(x0.y, f11, acc0);
        acc0 = fmaf(x0.z, f12, acc0); acc0 = fmaf(x0.w, f13, acc0);
        acc1 = fmaf(x1.x, f10, acc1); acc1 = fmaf(x1.y, f11, acc1);
        acc1 = fmaf(x1.z, f12, acc1); acc1 = fmaf(x1.w, f13, acc1);
        acc2 = fmaf(x2.x, f10, acc2); acc2 = fmaf(x2.y, f11, acc2);
        acc2 = fmaf(x2.z, f12, acc2); acc2 = fmaf(x2.w, f13, acc2);
    }

    // fold f0 (input dim 0) for this lane's k over the 3 a-rows
    float mu0 = mus[lane * 4 + 0];
    float rv0 = 0.5f * expf(-log_vars[lane * 4 + 0]);
    float g0 = (float)(a0 + 0) * (1.0f / 95.0f) - mu0;
    float g1 = (float)(a0 + 1) * (1.0f / 95.0f) - mu0;
    float g2 = (float)(a0 + 2) * (1.0f / 95.0f) - mu0;
    float yp = expf(-(g0 * g0) * rv0) * acc0
             + expf(-(g1 * g1) * rv0) * acc1
             + expf(-(g2 * g2) * rv0) * acc2;

    part[w][lane] = yp;
    __syncthreads();
    if (tid < KCOMP) {
        float s = 0.0f;
        #pragma unroll
        for (int q = 0; q < 8; ++q) s += part[q][tid];
        ws[YP_OFF + (b * 8 + aq) * KCOMP + tid] = s;
    }
}

// ---------------------------------------------------------------------------
// Kernel B: 256 blocks (b = bid>>3, oc = bid&7) x 576 threads. No exps.
//  - Stage G1 = F3 (float4 copies), build YG0[k][cl] = (sum_q Yp[b][q][k]) *
//    F2[k][oc*12+cl]  (weights already folded into F2).
//  - Main: thread = (kq = tid/144, p = c-pair 0..5, dq = d-quad 0..23);
//    16 k-iters of {ds_read_b128 + ds_read_b64 -> 8 FMA}. Partials to pacc
//    (9-float stride: conflict-free b32), combined by 144 threads.
// ---------------------------------------------------------------------------
__global__ __launch_bounds__(576) void kB(const float* __restrict__ ws,
                                          const float* __restrict__ bias,
                                          float* __restrict__ out) {
    __shared__ float G1[KCOMP * DIMN];      // [k][d], 24 KB
    __shared__ float YG0[KCOMP * 12];       // [k][cl], 3 KB
    __shared__ float pacc[4 * 144 * 9];     // 20.25 KB

    const int tid = threadIdx.x;
    const int bid = blockIdx.x;
    const int b   = bid >> 3;
    const int oc  = bid & 7;

    // stage G1 <- F3 (global, L2-hot) as float4
    {
        const float4* F3g = (const float4*)(ws + F3_OFF);
        float4* G1v = (float4*)G1;
        #pragma unroll
        for (int i = tid; i < (KCOMP * DIMN) / 4; i += 576) G1v[i] = F3g[i];
    }
    // YG0[k][cl] = (sum_q Yp[b][q][k]) * F2[k][oc*12+cl]
    {
        const float* F2g = ws + F2_OFF;
        const float* Ypb = ws + YP_OFF + b * 8 * KCOMP;
        for (int idx = tid; idx < KCOMP * 12; idx += 576) {
            int k  = idx / 12;
            int cl = idx - k * 12;
            float s = 0.0f;
            #pragma unroll
            for (int q = 0; q < 8; ++q) s += Ypb[q * KCOMP + k];
            YG0[idx] = s * F2g[k * DIMN + oc * 12 + cl];
        }
    }
    __syncthreads();

    // main rank-64 update, k split 4 ways
    {
        const int kq = tid / 144;           // 0..3
        const int r  = tid - kq * 144;      // 0..143
        const int p  = r / 24;              // c-pair
        const int dq = r - p * 24;          // d-quad
        const int k0 = kq * 16;

        float a0 = 0, a1 = 0, a2 = 0, a3 = 0, a4 = 0, a5 = 0, a6 = 0, a7 = 0;
        #pragma unroll 8
        for (int kk = 0; kk < 16; ++kk) {
            int k = k0 + kk;
            const float4 g = *(const float4*)&G1[k * DIMN + dq * 4];
            const float2 y = *(const float2*)&YG0[k * 12 + p * 2];
            a0 = fmaf(y.x, g.x, a0); a1 = fmaf(y.x, g.y, a1);
            a2 = fmaf(y.x, g.z, a2); a3 = fmaf(y.x, g.w, a3);
            a4 = fmaf(y.y, g.x, a4); a5 = fmaf(y.y, g.y, a5);
            a6 = fmaf(y.y, g.z, a6); a7 = fmaf(y.y, g.w, a7);
        }
        float* pa = &pacc[(kq * 144 + r) * 9];
        pa[0] = a0; pa[1] = a1; pa[2] = a2; pa[3] = a3;
        pa[4] = a4; pa[5] = a5; pa[6] = a6; pa[7] = a7;
    }
    __syncthreads();

    // combine 4 k-partials + bias + store
    if (tid < 144) {
        const int p  = tid / 24;
        const int dq = tid - p * 24;
        const int c0 = oc * 12 + p * 2;
        const int d0 = dq * 4;

        float s[8];
        #pragma unroll
        for (int j = 0; j < 8; ++j) {
            s[j] = pacc[(0 * 144 + tid) * 9 + j] + pacc[(1 * 144 + tid) * 9 + j]
                 + pacc[(2 * 144 + tid) * 9 + j] + pacc[(3 * 144 + tid) * 9 + j];
        }
        #pragma unroll
        for (int jr = 0; jr < 2; ++jr) {
            int o = (c0 + jr) * DIMN + d0;
            float4 bs = *(const float4*)&bias[o];
            *(float4*)&out[b * NUM_OUT + o] =
                make_float4(s[jr * 4 + 0] + bs.x, s[jr * 4 + 1] + bs.y,
                            s[jr * 4 + 2] + bs.z, s[jr * 4 + 3] + bs.w);
        }
    }
}

// ---------------------------------------------------------------------------
extern "C" void kernel_launch(void* const* d_in, const int* in_sizes, int n_in,
                              void* d_out, int out_size, void* d_ws, size_t ws_size,
                              hipStream_t stream) {
    const float* x        = (const float*)d_in[0];   // (32, 96, 96)
    const float* mus      = (const float*)d_in[1];   // (64, 4)
    const float* log_vars = (const float*)d_in[2];   // (64, 4)
    const float* weights  = (const float*)d_in[3];   // (64,)
    const float* bias     = (const float*)d_in[4];   // (9216,)
    float* out = (float*)d_out;                      // (32, 96, 96)
    float* ws  = (float*)d_ws;

    kA<<<280, 512, 0, stream>>>(x, mus, log_vars, weights, ws);
    kB<<<256, 576, 0, stream>>>(ws, bias, out);
}